// Round 4
// baseline (837.282 us; speedup 1.0000x reference)
//
#include <hip/hip_runtime.h>

// SNN B=128, D0=512, T=512, dims 1024/1024/512, DECAY=0.5, THRESH=0.3
// Round 15: bit-layers -> 4-buffer counted-vmcnt pipeline (T3+T4+T5).
//  - BK=32, buffers 16 KB (hi 8K + lo 8K) x4 rotating + 16 KB bits = 80 KB LDS
//    (2 blocks/CU exactly). Depth-3 prefetch: step i issues loads for i+3;
//    per step: s_waitcnt vmcnt(8) (counted, never 0 mid-loop) + one barrier.
//  - s_setprio(1) around each 8-MFMA cluster.
//  - Stage swizzle = L0's verified BK=32 geometry (key (row>>1)&3); bit
//    expansion = r14-wide's verified half-word logic.
//  - L0 unchanged from r13 (+setprio). Global K order and per-acc MFMA
//    sequence identical to r13 -> absmax=0 preserved.

typedef __bf16 bf16;
typedef __attribute__((ext_vector_type(8))) __bf16 bf16x8;
typedef __attribute__((ext_vector_type(16))) float f32x16;
typedef unsigned long long u64;

#define B_   128
#define D0_  512
#define T_   512
#define TS_  128
#define N1_  1024
#define N2_  1024
#define N3_  512
#define MFMA32(a,b,c) __builtin_amdgcn_mfma_f32_32x32x16_bf16((a),(b),(c),0,0,0)

#define GL2LDS(g, l) __builtin_amdgcn_global_load_lds( \
    (const __attribute__((address_space(1))) void*)(g), \
    (__attribute__((address_space(3))) void*)(l), 16, 0, 0)

#define WAIT_BARRIER() do { \
    asm volatile("s_waitcnt vmcnt(0)" ::: "memory"); \
    __builtin_amdgcn_s_barrier(); } while (0)

// ---------- setup ----------

__global__ __launch_bounds__(256)
void split_w(const float* __restrict__ W, bf16* __restrict__ WTh, bf16* __restrict__ WTl,
             int K, int N)
{
    __shared__ float tile[32][33];
    const int k0 = blockIdx.x * 32, n0 = blockIdx.y * 32;
    const int tx = threadIdx.x & 31, ty = threadIdx.x >> 5;
#pragma unroll
    for (int r = 0; r < 4; ++r)
        tile[ty + r * 8][tx] = W[(size_t)(k0 + ty + r * 8) * N + n0 + tx];
    __syncthreads();
#pragma unroll
    for (int r = 0; r < 4; ++r) {
        int nl = ty + r * 8;
        float v = tile[tx][nl];
        bf16 h = (bf16)v;
        size_t o = (size_t)(n0 + nl) * K + k0 + tx;
        WTh[o] = h;
        WTl[o] = (bf16)(v - (float)h);
    }
}

// x [B][D0][T] fp32 -> Xh/Xl slice-major [s][b][tl][D0] bf16 (hi/lo)
__global__ __launch_bounds__(256)
void split_x(const float* __restrict__ in, bf16* __restrict__ Xh, bf16* __restrict__ Xl)
{
    __shared__ float tile[32][33];
    const int b = blockIdx.z, d0 = blockIdx.x * 32, t0 = blockIdx.y * 32;
    const int tx = threadIdx.x & 31, ty = threadIdx.x >> 5;
#pragma unroll
    for (int r = 0; r < 4; ++r)
        tile[ty + r * 8][tx] = in[((size_t)b * D0_ + d0 + ty + r * 8) * T_ + t0 + tx];
    __syncthreads();
    const int s = t0 >> 7;
#pragma unroll
    for (int r = 0; r < 4; ++r) {
        int t  = t0 + ty + r * 8;
        int tl = t & (TS_ - 1);
        float v = tile[tx][ty + r * 8];
        bf16 h = (bf16)v;
        size_t o = (((size_t)s * B_ + b) * TS_ + tl) * D0_ + d0 + tx;
        Xh[o] = h;
        Xl[o] = (bf16)(v - (float)h);
    }
}

// 8 bits -> bf16x8 of {0.0, 1.0} (exact).
__device__ __forceinline__ bf16x8 expand8(unsigned v)
{
    union { unsigned u[4]; bf16x8 h; } r;
    const unsigned p = v * 0x8001u;
#pragma unroll
    for (int i = 0; i < 4; ++i)
        r.u[i] = ((p >> (2 * i)) & 0x10001u) * 0x3F80u;
    return r.h;
}

// ---------- layer 0: Xh/Xl @ W0 (3-term), BK=32, 2-phase dbuf (r13) ----------
__global__ __launch_bounds__(256, 2)
void snn_layer0(const bf16* __restrict__ Ah, const bf16* __restrict__ Al,
                const bf16* __restrict__ WTh, const bf16* __restrict__ WTl,
                u64* __restrict__ bitsOut)
{
    constexpr int K = D0_;
    __shared__ char smem[65536];
    bf16* sA0  = (bf16*)(smem);
    bf16* sAl0 = (bf16*)(smem + 8192);
    bf16* sB0  = (bf16*)(smem + 16384);
    bf16* sBl0 = (bf16*)(smem + 24576);
    bf16* sA1  = (bf16*)(smem + 32768);
    bf16* sAl1 = (bf16*)(smem + 40960);
    bf16* sB1  = (bf16*)(smem + 49152);
    bf16* sBl1 = (bf16*)(smem + 57344);
    float* If  = (float*)smem;

    const int tid = threadIdx.x, lane = tid & 63, w = tid >> 6;
    const int wm = w & 1, wn = w >> 1;
    const int l31 = lane & 31, kh = lane >> 5;
    const int b = blockIdx.x;
    const int nb = blockIdx.y * 128;

    const int i4 = lane >> 2, c4 = lane & 3;
    const int csrc = c4 ^ ((i4 >> 1) & 3);
    const bf16* gBh = WTh + (size_t)(nb + w * 32 + i4) * K + csrc * 8;
    const bf16* gBl = WTl + (size_t)(nb + w * 32 + i4) * K + csrc * 8;
    const int wT = w * 32 * 32;

    int rA[2], rB[2], swA[2], swB[2];
#pragma unroll
    for (int i = 0; i < 2; ++i) {
        rA[i] = wm * 64 + i * 32 + l31;
        rB[i] = wn * 64 + i * 32 + l31;
        swA[i] = (rA[i] >> 1) & 3;
        swB[i] = (rB[i] >> 1) & 3;
    }

    float cm = 0.f, cs = 0.f;
    const int scol = tid & 63;
    float* Ifb = If + (tid >> 6) * 4096;

#define STAGE0(dA, dAl, dBh, dBl, go)                                          \
    do {                                                                       \
        _Pragma("unroll")                                                      \
        for (int inst = 0; inst < 2; ++inst) {                                 \
            GL2LDS(gA  + (size_t)(inst * 16) * K + (go), (dA)  + wT + inst * 16 * 32); \
            GL2LDS(gAl + (size_t)(inst * 16) * K + (go), (dAl) + wT + inst * 16 * 32); \
            GL2LDS(gBh + (size_t)(inst * 16) * K + (go), (dBh) + wT + inst * 16 * 32); \
            GL2LDS(gBl + (size_t)(inst * 16) * K + (go), (dBl) + wT + inst * 16 * 32); \
        }                                                                      \
    } while (0)

#define KSTEP0(cA, cAl, cBh, cBl)                                              \
    do {                                                                       \
        bf16x8 a[2][2], al2[2][2];                                             \
        _Pragma("unroll")                                                      \
        for (int mi = 0; mi < 2; ++mi)                                         \
            _Pragma("unroll")                                                  \
            for (int h = 0; h < 2; ++h) {                                      \
                const int off = rA[mi] * 32 + (((2 * h + kh) ^ swA[mi]) * 8);  \
                a[mi][h]   = *(const bf16x8*)((cA) + off);                     \
                al2[mi][h] = *(const bf16x8*)((cAl) + off);                    \
            }                                                                  \
        __builtin_amdgcn_s_setprio(1);                                         \
        _Pragma("unroll")                                                      \
        for (int ni = 0; ni < 2; ++ni) {                                       \
            _Pragma("unroll")                                                  \
            for (int h = 0; h < 2; ++h) {                                      \
                const int off = rB[ni] * 32 + (((2 * h + kh) ^ swB[ni]) * 8);  \
                bf16x8 bh = *(const bf16x8*)((cBh) + off);                     \
                bf16x8 bl = *(const bf16x8*)((cBl) + off);                     \
                _Pragma("unroll")                                              \
                for (int mi = 0; mi < 2; ++mi) {                               \
                    acc[mi][ni] = MFMA32(a[mi][h], bh, acc[mi][ni]);           \
                    acc[mi][ni] = MFMA32(al2[mi][h], bh, acc[mi][ni]);         \
                    acc[mi][ni] = MFMA32(a[mi][h], bl, acc[mi][ni]);           \
                }                                                              \
            }                                                                  \
        }                                                                      \
        __builtin_amdgcn_s_setprio(0);                                         \
        WAIT_BARRIER();                                                        \
    } while (0)

#pragma unroll 1
    for (int s = 0; s < T_ / TS_; ++s) {
        const size_t arow = ((size_t)s * B_ + b) * TS_;
        const bf16* gA  = Ah + (arow + w * 32 + i4) * K + csrc * 8;
        const bf16* gAl = Al + (arow + w * 32 + i4) * K + csrc * 8;

        STAGE0(sA0, sAl0, sB0, sBl0, 0);
        WAIT_BARRIER();

        f32x16 acc[2][2] = {};

#pragma unroll 1
        for (int ks = 0; ks < K / 32; ks += 2) {
            STAGE0(sA1, sAl1, sB1, sBl1, (ks + 1) * 32);
            KSTEP0(sA0, sAl0, sB0, sBl0);
            if (ks + 2 < K / 32)
                STAGE0(sA0, sAl0, sB0, sBl0, (ks + 2) * 32);
            KSTEP0(sA1, sAl1, sB1, sBl1);
        }

        u64 word0 = 0, word1 = 0;
        if (wm == 0) {
#pragma unroll
            for (int ni = 0; ni < 2; ++ni)
#pragma unroll
                for (int mi = 0; mi < 2; ++mi)
#pragma unroll
                    for (int r = 0; r < 16; ++r) {
                        const int tt = mi * 32 + (r & 3) + 8 * (r >> 2) + 4 * kh;
                        If[wn * 4096 + tt * 64 + ni * 32 + l31] = acc[mi][ni][r];
                    }
        }
        __syncthreads();
        if (tid < 128) {
            float m = cm, sp = cs;
#pragma unroll 4
            for (int tt = 0; tt < 64; ++tt) {
                m = m * 0.5f * (1.0f - sp) + Ifb[tt * 64 + scol];
                const bool fire = m > 0.3f;
                sp = fire ? 1.0f : 0.0f;
                u64 bal = __ballot(fire);
                if ((tid & 63) == tt) word0 = bal;
            }
            cm = m; cs = sp;
        }
        __syncthreads();
        if (wm == 1) {
#pragma unroll
            for (int ni = 0; ni < 2; ++ni)
#pragma unroll
                for (int mi = 0; mi < 2; ++mi)
#pragma unroll
                    for (int r = 0; r < 16; ++r) {
                        const int tt = mi * 32 + (r & 3) + 8 * (r >> 2) + 4 * kh;
                        If[wn * 4096 + tt * 64 + ni * 32 + l31] = acc[mi][ni][r];
                    }
        }
        __syncthreads();
        if (tid < 128) {
            float m = cm, sp = cs;
#pragma unroll 4
            for (int tt = 0; tt < 64; ++tt) {
                m = m * 0.5f * (1.0f - sp) + Ifb[tt * 64 + scol];
                const bool fire = m > 0.3f;
                sp = fire ? 1.0f : 0.0f;
                u64 bal = __ballot(fire);
                if ((tid & 63) == tt) word1 = bal;
            }
            cm = m; cs = sp;
            u64* dst = bitsOut + ((size_t)s * B_ + b) * 2048;
            const int j8 = (nb >> 6) + (tid >> 6);
            const int t0 = tid & 63, t1 = 64 + (tid & 63);
            dst[t0 * 16 + (j8 ^ (t0 & 15))] = word0;
            dst[t1 * 16 + (j8 ^ (t1 & 15))] = word1;
        }
        __syncthreads();
    }
#undef STAGE0
#undef KSTEP0
}

// ---------- bit-layers: BK=32, 4-buffer counted-vmcnt pipeline ----------
// LDS: bits 16K @0; buffers j=0..3 @16384+j*16384 (hi 8K, lo 8K). 80 KB total.
// Step i: wait vmcnt(8); barrier; issue loads(i+3) -> buf (i+3)%4; compute buf i%4.
template<bool WRITE_BITS>
__global__ __launch_bounds__(256, 2)
void snn_layer_bits(const u64* __restrict__ bitsIn,
                    const bf16* __restrict__ WTh, const bf16* __restrict__ WTl,
                    u64* __restrict__ bitsOut, float* __restrict__ outp, int N)
{
    constexpr int K = 1024;
    __shared__ char smem[81920];
    char* bitsLds = smem;                       // [0,16K): bit tile [128 t][16 u64]
    float* If = (float*)(smem + 16384);         // epilogue overlay (32 KB = bufs 0,1)

#define SBUF_H(j) ((bf16*)(smem + 16384 + (j) * 16384))
#define SBUF_L(j) ((bf16*)(smem + 16384 + (j) * 16384 + 8192))

    const int tid = threadIdx.x, lane = tid & 63, w = tid >> 6;
    const int wm = w & 1, wn = w >> 1;
    const int l31 = lane & 31, kh = lane >> 5;
    const int b = blockIdx.x;
    const int nb = blockIdx.y * 128;

    // B staging (BK=32): per tensor per wave 2 insts of 16 rows x 64 B;
    // rows w*32 + inst*16 + i4, chunk pre-swizzled with key (i4>>1)&3.
    const int i4 = lane >> 2, c4 = lane & 3;
    const int csrc = c4 ^ ((i4 >> 1) & 3);
    const bf16* gBh = WTh + (size_t)(nb + w * 32 + i4) * K + csrc * 8;
    const bf16* gBl = WTl + (size_t)(nb + w * 32 + i4) * K + csrc * 8;
    const int wOff = (w * 32) * 32;             // wave's 2 KB chunk (elements)

    int rA[2], rB[2], swB[2];
#pragma unroll
    for (int i = 0; i < 2; ++i) {
        rA[i] = wm * 64 + i * 32 + l31;
        rB[i] = wn * 64 + i * 32 + l31;
        swB[i] = (rB[i] >> 1) & 3;
    }
    const int sh8 = 8 * kh;
    const int bA0 = rA[0] * 128, bA1 = rA[1] * 128;
    const int s15a = rA[0] & 15, s15b = rA[1] & 15;

    float cm = 0.f, cs = 0.f;
    const int scol = tid & 63;
    float* Ifb = If + (tid >> 6) * 4096;

#define STAGEN(j, go)                                                          \
    do {                                                                       \
        GL2LDS(gBh + (size_t)(go),              SBUF_H(j) + wOff);             \
        GL2LDS(gBh + (size_t)16 * K + (go),     SBUF_H(j) + wOff + 512);       \
        GL2LDS(gBl + (size_t)(go),              SBUF_L(j) + wOff);             \
        GL2LDS(gBl + (size_t)16 * K + (go),     SBUF_L(j) + wOff + 512);       \
    } while (0)

#define KSTEPN(j, x0, x1)                                                      \
    do {                                                                       \
        _Pragma("unroll")                                                      \
        for (int h = 0; h < 2; ++h) {                                          \
            bf16x8 a0 = expand8(((x0) >> (16 * h + sh8)) & 0xFFu);             \
            bf16x8 a1 = expand8(((x1) >> (16 * h + sh8)) & 0xFFu);             \
            __builtin_amdgcn_s_setprio(1);                                     \
            _Pragma("unroll")                                                  \
            for (int ni = 0; ni < 2; ++ni) {                                   \
                const int off = rB[ni] * 32 + (((2 * h + kh) ^ swB[ni]) * 8);  \
                bf16x8 bh = *(const bf16x8*)(SBUF_H(j) + off);                 \
                bf16x8 bl = *(const bf16x8*)(SBUF_L(j) + off);                 \
                acc[0][ni] = MFMA32(a0, bh, acc[0][ni]);                       \
                acc[0][ni] = MFMA32(a0, bl, acc[0][ni]);                       \
                acc[1][ni] = MFMA32(a1, bh, acc[1][ni]);                       \
                acc[1][ni] = MFMA32(a1, bl, acc[1][ni]);                       \
            }                                                                  \
            __builtin_amdgcn_s_setprio(0);                                     \
        }                                                                      \
    } while (0)

// ks must have statically-known parity (base multiple of 4 + literal offset)
#define STEPN(ks, bufj, issj, DOISS, VMN)                                      \
    do {                                                                       \
        asm volatile("s_waitcnt vmcnt(" VMN ")" ::: "memory");                 \
        __builtin_amdgcn_s_barrier();                                          \
        if (DOISS) STAGEN(issj, ((ks) + 3) * 32);                              \
        const u64 wa0_ = *(const u64*)(bitsLds + bA0 + ((((ks) >> 1) ^ s15a) << 3)); \
        const u64 wa1_ = *(const u64*)(bitsLds + bA1 + ((((ks) >> 1) ^ s15b) << 3)); \
        const unsigned x0_ = (unsigned)(wa0_ >> (32 * ((ks) & 1)));            \
        const unsigned x1_ = (unsigned)(wa1_ >> (32 * ((ks) & 1)));            \
        KSTEPN(bufj, x0_, x1_);                                                \
    } while (0)

#pragma unroll 1
    for (int s = 0; s < T_ / TS_; ++s) {
        // slice prologue: bits tile (4 GL2LDS/wave) + B buffers 0,1,2
        {
            const char* src = (const char*)bitsIn + ((size_t)s * B_ + b) * 16384;
#pragma unroll
            for (int i = 0; i < 4; ++i)
                GL2LDS(src + (w * 4 + i) * 1024 + lane * 16,
                       bitsLds + (w * 4 + i) * 1024);
        }
        STAGEN(0, 0);
        STAGEN(1, 32);
        STAGEN(2, 64);

        f32x16 acc[2][2] = {};

        // main: steps 0..27 (7 x 4-unrolled), depth-3 prefetch, vmcnt(8)
#pragma unroll 1
        for (int base = 0; base < 28; base += 4) {
            STEPN(base + 0, 0, 3, true, "8");
            STEPN(base + 1, 1, 0, true, "8");
            STEPN(base + 2, 2, 1, true, "8");
            STEPN(base + 3, 3, 2, true, "8");
        }
        // tail: step 28 issues ks=31 (last); 29..31 drain with counted waits
        STEPN(28, 0, 3, true,  "8");
        STEPN(29, 1, 0, false, "8");
        STEPN(30, 2, 0, false, "4");
        STEPN(31, 3, 0, false, "0");

        // ---- epilogue: 2-phase LIF scan + ballot bit-transpose ----
        u64 word0 = 0, word1 = 0;
        if (wm == 0) {
#pragma unroll
            for (int ni = 0; ni < 2; ++ni)
#pragma unroll
                for (int mi = 0; mi < 2; ++mi)
#pragma unroll
                    for (int r = 0; r < 16; ++r) {
                        const int tt = mi * 32 + (r & 3) + 8 * (r >> 2) + 4 * kh;
                        If[wn * 4096 + tt * 64 + ni * 32 + l31] = acc[mi][ni][r];
                    }
        }
        __syncthreads();
        if (tid < 128) {
            float m = cm, sp = cs;
#pragma unroll 4
            for (int tt = 0; tt < 64; ++tt) {
                m = m * 0.5f * (1.0f - sp) + Ifb[tt * 64 + scol];
                const bool fire = m > 0.3f;
                sp = fire ? 1.0f : 0.0f;
                if constexpr (WRITE_BITS) {
                    u64 bal = __ballot(fire);
                    if ((tid & 63) == tt) word0 = bal;
                }
            }
            cm = m; cs = sp;
        }
        __syncthreads();
        if (wm == 1) {
#pragma unroll
            for (int ni = 0; ni < 2; ++ni)
#pragma unroll
                for (int mi = 0; mi < 2; ++mi)
#pragma unroll
                    for (int r = 0; r < 16; ++r) {
                        const int tt = mi * 32 + (r & 3) + 8 * (r >> 2) + 4 * kh;
                        If[wn * 4096 + tt * 64 + ni * 32 + l31] = acc[mi][ni][r];
                    }
        }
        __syncthreads();
        if (tid < 128) {
            float m = cm, sp = cs;
#pragma unroll 4
            for (int tt = 0; tt < 64; ++tt) {
                m = m * 0.5f * (1.0f - sp) + Ifb[tt * 64 + scol];
                const bool fire = m > 0.3f;
                sp = fire ? 1.0f : 0.0f;
                if constexpr (WRITE_BITS) {
                    u64 bal = __ballot(fire);
                    if ((tid & 63) == tt) word1 = bal;
                }
            }
            cm = m; cs = sp;
            if constexpr (WRITE_BITS) {
                u64* dst = bitsOut + ((size_t)s * B_ + b) * 2048;
                const int j8 = (nb >> 6) + (tid >> 6);
                const int t0 = tid & 63, t1 = 64 + (tid & 63);
                dst[t0 * 16 + (j8 ^ (t0 & 15))] = word0;
                dst[t1 * 16 + (j8 ^ (t1 & 15))] = word1;
            } else {
                if (s == T_ / TS_ - 1)
                    outp[(size_t)b * N + nb + tid] = cs;
            }
        }
        __syncthreads();   // protect bits + bufs before next slice's prologue
    }
#undef STAGEN
#undef KSTEPN
#undef STEPN
#undef SBUF_H
#undef SBUF_L
}

extern "C" void kernel_launch(void* const* d_in, const int* in_sizes, int n_in,
                              void* d_out, int out_size, void* d_ws, size_t ws_size,
                              hipStream_t stream)
{
    const float* x  = (const float*)d_in[0];
    const float* w0 = (const float*)d_in[1];
    const float* w1 = (const float*)d_in[2];
    const float* w2 = (const float*)d_in[3];
    float* out = (float*)d_out;

    char* p = (char*)d_ws;
    bf16* w0h = (bf16*)p;  p += (size_t)N1_ * D0_ * 2;
    bf16* w0l = (bf16*)p;  p += (size_t)N1_ * D0_ * 2;
    bf16* w1h = (bf16*)p;  p += (size_t)N2_ * N1_ * 2;
    bf16* w1l = (bf16*)p;  p += (size_t)N2_ * N1_ * 2;
    bf16* w2h = (bf16*)p;  p += (size_t)N3_ * N2_ * 2;
    bf16* w2l = (bf16*)p;  p += (size_t)N3_ * N2_ * 2;
    bf16* Xh  = (bf16*)p;  p += (size_t)T_ * B_ * D0_ * 2;
    bf16* Xl  = (bf16*)p;  p += (size_t)T_ * B_ * D0_ * 2;
    u64* bits0 = (u64*)p;  p += (size_t)(T_/TS_) * B_ * TS_ * (N1_/8);
    u64* bits1 = (u64*)p;  p += (size_t)(T_/TS_) * B_ * TS_ * (N2_/8);

    split_w<<<dim3(D0_/32, N1_/32), 256, 0, stream>>>(w0, w0h, w0l, D0_, N1_);
    split_w<<<dim3(N1_/32, N2_/32), 256, 0, stream>>>(w1, w1h, w1l, N1_, N2_);
    split_w<<<dim3(N2_/32, N3_/32), 256, 0, stream>>>(w2, w2h, w2l, N2_, N3_);
    split_x<<<dim3(D0_/32, T_/32, B_), 256, 0, stream>>>(x, Xh, Xl);

    // L0: X@w0 (3-term split) + LIF -> bit train
    snn_layer0<<<dim3(B_, N1_/128), 256, 0, stream>>>(Xh, Xl, w0h, w0l, bits0);
    // L1: bits0@w1 + LIF -> bit train
    snn_layer_bits<true ><<<dim3(B_, N2_/128), 256, 0, stream>>>(
        bits0, w1h, w1l, bits1, nullptr, N2_);
    // L2: bits1@w2 + LIF -> final spikes to d_out
    snn_layer_bits<false><<<dim3(B_, N3_/128), 256, 0, stream>>>(
        bits1, w2h, w2l, nullptr, out, N3_);
}

// Round 5
// 801.524 us; speedup vs baseline: 1.0446x; 1.0446x over previous
//
#include <hip/hip_runtime.h>

// SNN B=128, D0=512, T=512, dims 1024/1024/512, DECAY=0.5, THRESH=0.3
// Round 16 = r13 baseline (best: 804 us) + three additive deltas:
//  1. Cross-chain MFMA interleave: 4 independent acc chains emitted
//     round-robin (dependent MFMAs >=4 apart). Per-element update order
//     unchanged (h asc, hi before lo) -> absmax=0 preserved.
//  2. L0 XCD-grouping swizzle: flat grid 1024, b = bid%8 + 8*(bid/64),
//     nb = (bid/8)%8 -> all 8 nb-blocks of a batch-row land on one XCD,
//     X slice becomes L2-resident instead of 8x L3/HBM re-read.
//  3. L1/L2 grid dims swapped (nb fastest) -> same weight panel per XCD.
// L1/L2 GEMM core = r13 (BK=64, 2-phase dbuf, 80 KB LDS).

typedef __bf16 bf16;
typedef __attribute__((ext_vector_type(8))) __bf16 bf16x8;
typedef __attribute__((ext_vector_type(16))) float f32x16;
typedef unsigned long long u64;

#define B_   128
#define D0_  512
#define T_   512
#define TS_  128
#define N1_  1024
#define N2_  1024
#define N3_  512
#define MFMA32(a,b,c) __builtin_amdgcn_mfma_f32_32x32x16_bf16((a),(b),(c),0,0,0)

#define GL2LDS(g, l) __builtin_amdgcn_global_load_lds( \
    (const __attribute__((address_space(1))) void*)(g), \
    (__attribute__((address_space(3))) void*)(l), 16, 0, 0)

#define WAIT_BARRIER() do { \
    asm volatile("s_waitcnt vmcnt(0)" ::: "memory"); \
    __builtin_amdgcn_s_barrier(); } while (0)

// ---------- setup ----------

__global__ __launch_bounds__(256)
void split_w(const float* __restrict__ W, bf16* __restrict__ WTh, bf16* __restrict__ WTl,
             int K, int N)
{
    __shared__ float tile[32][33];
    const int k0 = blockIdx.x * 32, n0 = blockIdx.y * 32;
    const int tx = threadIdx.x & 31, ty = threadIdx.x >> 5;
#pragma unroll
    for (int r = 0; r < 4; ++r)
        tile[ty + r * 8][tx] = W[(size_t)(k0 + ty + r * 8) * N + n0 + tx];
    __syncthreads();
#pragma unroll
    for (int r = 0; r < 4; ++r) {
        int nl = ty + r * 8;
        float v = tile[tx][nl];
        bf16 h = (bf16)v;
        size_t o = (size_t)(n0 + nl) * K + k0 + tx;
        WTh[o] = h;
        WTl[o] = (bf16)(v - (float)h);
    }
}

// x [B][D0][T] fp32 -> Xh/Xl slice-major [s][b][tl][D0] bf16 (hi/lo)
__global__ __launch_bounds__(256)
void split_x(const float* __restrict__ in, bf16* __restrict__ Xh, bf16* __restrict__ Xl)
{
    __shared__ float tile[32][33];
    const int b = blockIdx.z, d0 = blockIdx.x * 32, t0 = blockIdx.y * 32;
    const int tx = threadIdx.x & 31, ty = threadIdx.x >> 5;
#pragma unroll
    for (int r = 0; r < 4; ++r)
        tile[ty + r * 8][tx] = in[((size_t)b * D0_ + d0 + ty + r * 8) * T_ + t0 + tx];
    __syncthreads();
    const int s = t0 >> 7;
#pragma unroll
    for (int r = 0; r < 4; ++r) {
        int t  = t0 + ty + r * 8;
        int tl = t & (TS_ - 1);
        float v = tile[tx][ty + r * 8];
        bf16 h = (bf16)v;
        size_t o = (((size_t)s * B_ + b) * TS_ + tl) * D0_ + d0 + tx;
        Xh[o] = h;
        Xl[o] = (bf16)(v - (float)h);
    }
}

// 8 bits -> bf16x8 of {0.0, 1.0} (exact).
__device__ __forceinline__ bf16x8 expand8(unsigned v)
{
    union { unsigned u[4]; bf16x8 h; } r;
    const unsigned p = v * 0x8001u;
#pragma unroll
    for (int i = 0; i < 4; ++i)
        r.u[i] = ((p >> (2 * i)) & 0x10001u) * 0x3F80u;
    return r.h;
}

// ---------- layer 0: Xh/Xl @ W0 (3-term), BK=32, 2-phase dbuf ----------
// Flat grid 1024; same-b blocks grouped onto one XCD (bid%8 == b%8).
__global__ __launch_bounds__(256, 2)
void snn_layer0(const bf16* __restrict__ Ah, const bf16* __restrict__ Al,
                const bf16* __restrict__ WTh, const bf16* __restrict__ WTl,
                u64* __restrict__ bitsOut)
{
    constexpr int K = D0_;
    __shared__ char smem[65536];
    bf16* sA0  = (bf16*)(smem);
    bf16* sAl0 = (bf16*)(smem + 8192);
    bf16* sB0  = (bf16*)(smem + 16384);
    bf16* sBl0 = (bf16*)(smem + 24576);
    bf16* sA1  = (bf16*)(smem + 32768);
    bf16* sAl1 = (bf16*)(smem + 40960);
    bf16* sB1  = (bf16*)(smem + 49152);
    bf16* sBl1 = (bf16*)(smem + 57344);
    float* If  = (float*)smem;

    const int tid = threadIdx.x, lane = tid & 63, w = tid >> 6;
    const int wm = w & 1, wn = w >> 1;
    const int l31 = lane & 31, kh = lane >> 5;
    const int bid = blockIdx.x;
    const int b  = (bid & 7) | ((bid >> 6) << 3);    // bid%8 + 8*(bid/64)
    const int nb = ((bid >> 3) & 7) * 128;

    const int i4 = lane >> 2, c4 = lane & 3;
    const int csrc = c4 ^ ((i4 >> 1) & 3);
    const bf16* gBh = WTh + (size_t)(nb + w * 32 + i4) * K + csrc * 8;
    const bf16* gBl = WTl + (size_t)(nb + w * 32 + i4) * K + csrc * 8;
    const int wT = w * 32 * 32;

    int rA[2], rB[2], swA[2], swB[2];
#pragma unroll
    for (int i = 0; i < 2; ++i) {
        rA[i] = wm * 64 + i * 32 + l31;
        rB[i] = wn * 64 + i * 32 + l31;
        swA[i] = (rA[i] >> 1) & 3;
        swB[i] = (rB[i] >> 1) & 3;
    }

    float cm = 0.f, cs = 0.f;
    const int scol = tid & 63;
    float* Ifb = If + (tid >> 6) * 4096;

#define STAGE0(dA, dAl, dBh, dBl, go)                                          \
    do {                                                                       \
        _Pragma("unroll")                                                      \
        for (int inst = 0; inst < 2; ++inst) {                                 \
            GL2LDS(gA  + (size_t)(inst * 16) * K + (go), (dA)  + wT + inst * 16 * 32); \
            GL2LDS(gAl + (size_t)(inst * 16) * K + (go), (dAl) + wT + inst * 16 * 32); \
            GL2LDS(gBh + (size_t)(inst * 16) * K + (go), (dBh) + wT + inst * 16 * 32); \
            GL2LDS(gBl + (size_t)(inst * 16) * K + (go), (dBl) + wT + inst * 16 * 32); \
        }                                                                      \
    } while (0)

// Cross-chain interleave: per h, emit term-hh for all 4 (mi,ni) chains, then
// term-lh, then term-hl. Per-element order (h asc; hh, lh, hl) == r13.
#define KSTEP0(cA, cAl, cBh, cBl)                                              \
    do {                                                                       \
        bf16x8 a[2][2], al2[2][2];                                             \
        _Pragma("unroll")                                                      \
        for (int mi = 0; mi < 2; ++mi)                                         \
            _Pragma("unroll")                                                  \
            for (int h = 0; h < 2; ++h) {                                      \
                const int off = rA[mi] * 32 + (((2 * h + kh) ^ swA[mi]) * 8);  \
                a[mi][h]   = *(const bf16x8*)((cA) + off);                     \
                al2[mi][h] = *(const bf16x8*)((cAl) + off);                    \
            }                                                                  \
        _Pragma("unroll")                                                      \
        for (int h = 0; h < 2; ++h) {                                          \
            bf16x8 bh[2], bl[2];                                               \
            _Pragma("unroll")                                                  \
            for (int ni = 0; ni < 2; ++ni) {                                   \
                const int off = rB[ni] * 32 + (((2 * h + kh) ^ swB[ni]) * 8);  \
                bh[ni] = *(const bf16x8*)((cBh) + off);                        \
                bl[ni] = *(const bf16x8*)((cBl) + off);                        \
            }                                                                  \
            _Pragma("unroll")                                                  \
            for (int ni = 0; ni < 2; ++ni)                                     \
                _Pragma("unroll")                                              \
                for (int mi = 0; mi < 2; ++mi)                                 \
                    acc[mi][ni] = MFMA32(a[mi][h], bh[ni], acc[mi][ni]);       \
            _Pragma("unroll")                                                  \
            for (int ni = 0; ni < 2; ++ni)                                     \
                _Pragma("unroll")                                              \
                for (int mi = 0; mi < 2; ++mi)                                 \
                    acc[mi][ni] = MFMA32(al2[mi][h], bh[ni], acc[mi][ni]);     \
            _Pragma("unroll")                                                  \
            for (int ni = 0; ni < 2; ++ni)                                     \
                _Pragma("unroll")                                              \
                for (int mi = 0; mi < 2; ++mi)                                 \
                    acc[mi][ni] = MFMA32(a[mi][h], bl[ni], acc[mi][ni]);       \
        }                                                                      \
        WAIT_BARRIER();                                                        \
    } while (0)

#pragma unroll 1
    for (int s = 0; s < T_ / TS_; ++s) {
        const size_t arow = ((size_t)s * B_ + b) * TS_;
        const bf16* gA  = Ah + (arow + w * 32 + i4) * K + csrc * 8;
        const bf16* gAl = Al + (arow + w * 32 + i4) * K + csrc * 8;

        STAGE0(sA0, sAl0, sB0, sBl0, 0);
        WAIT_BARRIER();

        f32x16 acc[2][2] = {};

#pragma unroll 1
        for (int ks = 0; ks < K / 32; ks += 2) {
            STAGE0(sA1, sAl1, sB1, sBl1, (ks + 1) * 32);
            KSTEP0(sA0, sAl0, sB0, sBl0);
            if (ks + 2 < K / 32)
                STAGE0(sA0, sAl0, sB0, sBl0, (ks + 2) * 32);
            KSTEP0(sA1, sAl1, sB1, sBl1);
        }

        u64 word0 = 0, word1 = 0;
        if (wm == 0) {
#pragma unroll
            for (int ni = 0; ni < 2; ++ni)
#pragma unroll
                for (int mi = 0; mi < 2; ++mi)
#pragma unroll
                    for (int r = 0; r < 16; ++r) {
                        const int tt = mi * 32 + (r & 3) + 8 * (r >> 2) + 4 * kh;
                        If[wn * 4096 + tt * 64 + ni * 32 + l31] = acc[mi][ni][r];
                    }
        }
        __syncthreads();
        if (tid < 128) {
            float m = cm, sp = cs;
#pragma unroll 4
            for (int tt = 0; tt < 64; ++tt) {
                m = m * 0.5f * (1.0f - sp) + Ifb[tt * 64 + scol];
                const bool fire = m > 0.3f;
                sp = fire ? 1.0f : 0.0f;
                u64 bal = __ballot(fire);
                if ((tid & 63) == tt) word0 = bal;
            }
            cm = m; cs = sp;
        }
        __syncthreads();
        if (wm == 1) {
#pragma unroll
            for (int ni = 0; ni < 2; ++ni)
#pragma unroll
                for (int mi = 0; mi < 2; ++mi)
#pragma unroll
                    for (int r = 0; r < 16; ++r) {
                        const int tt = mi * 32 + (r & 3) + 8 * (r >> 2) + 4 * kh;
                        If[wn * 4096 + tt * 64 + ni * 32 + l31] = acc[mi][ni][r];
                    }
        }
        __syncthreads();
        if (tid < 128) {
            float m = cm, sp = cs;
#pragma unroll 4
            for (int tt = 0; tt < 64; ++tt) {
                m = m * 0.5f * (1.0f - sp) + Ifb[tt * 64 + scol];
                const bool fire = m > 0.3f;
                sp = fire ? 1.0f : 0.0f;
                u64 bal = __ballot(fire);
                if ((tid & 63) == tt) word1 = bal;
            }
            cm = m; cs = sp;
            u64* dst = bitsOut + ((size_t)s * B_ + b) * 2048;
            const int j8 = (nb >> 6) + (tid >> 6);
            const int t0 = tid & 63, t1 = 64 + (tid & 63);
            dst[t0 * 16 + (j8 ^ (t0 & 15))] = word0;
            dst[t1 * 16 + (j8 ^ (t1 & 15))] = word1;
        }
        __syncthreads();
    }
#undef STAGE0
#undef KSTEP0
}

// ---------- bit-layers (r13 core): bit-packed A, BK=64, 2-phase dbuf ----------
// Grid dims swapped: nb = blockIdx.x (fastest) -> same weight panel per XCD.
template<bool WRITE_BITS>
__global__ __launch_bounds__(256, 2)
void snn_layer_bits(const u64* __restrict__ bitsIn,
                    const bf16* __restrict__ WTh, const bf16* __restrict__ WTl,
                    u64* __restrict__ bitsOut, float* __restrict__ outp, int N)
{
    constexpr int K = 1024;
    __shared__ char smem[81920];
    char* bitsLds = smem;                       // [0,16K): bit tile [128 t][128 B]
    bf16* sBh0 = (bf16*)(smem + 16384);         // buf0 hi [128][64]
    bf16* sBl0 = (bf16*)(smem + 32768);         // buf0 lo
    bf16* sBh1 = (bf16*)(smem + 49152);         // buf1 hi
    bf16* sBl1 = (bf16*)(smem + 65536);         // buf1 lo
    float* If  = (float*)(smem + 16384);        // epilogue overlay (32 KB, =buf0)

    const int tid = threadIdx.x, lane = tid & 63, w = tid >> 6;
    const int wm = w & 1, wn = w >> 1;
    const int l31 = lane & 31, kh = lane >> 5;
    const int b = blockIdx.y;
    const int nb = blockIdx.x * 128;

    const int i8 = lane >> 3, c8 = lane & 7;
    const bf16* gBh = WTh + (size_t)(nb + w * 32 + i8) * K + (c8 ^ i8) * 8;
    const bf16* gBl = WTl + (size_t)(nb + w * 32 + i8) * K + (c8 ^ i8) * 8;
    const int wB = w * 32 * 64;

    int rA[2], rB[2];
#pragma unroll
    for (int i = 0; i < 2; ++i) {
        rA[i] = wm * 64 + i * 32 + l31;
        rB[i] = wn * 64 + i * 32 + l31;
    }
    const int sw7 = l31 & 7, sw15 = l31 & 15, sh8 = 8 * kh;

    float cm = 0.f, cs = 0.f;
    const int scol = tid & 63;
    float* Ifb = If + (tid >> 6) * 4096;

#define STAGEB(dBh, dBl, go)                                                   \
    do {                                                                       \
        _Pragma("unroll")                                                      \
        for (int inst = 0; inst < 4; ++inst) {                                 \
            GL2LDS(gBh + (size_t)(inst * 8) * K + (go), (dBh) + wB + inst * 8 * 64); \
            GL2LDS(gBl + (size_t)(inst * 8) * K + (go), (dBl) + wB + inst * 8 * 64); \
        }                                                                      \
    } while (0)

// Cross-chain interleave: per h, the 4 acc chains round-robin; per-element
// order (h asc; bh before bl) == r13 -> bit-exact.
#define KSTEPB(ks, cBh, cBl)                                                   \
    do {                                                                       \
        u64 wA0 = *(const u64*)(bitsLds + rA[0] * 128 + (((ks) ^ sw15) << 3)) >> sh8; \
        u64 wA1 = *(const u64*)(bitsLds + rA[1] * 128 + (((ks) ^ sw15) << 3)) >> sh8; \
        _Pragma("unroll")                                                      \
        for (int h = 0; h < 4; ++h) {                                          \
            bf16x8 a0 = expand8((unsigned)(wA0 >> (16 * h)) & 0xFFu);          \
            bf16x8 a1 = expand8((unsigned)(wA1 >> (16 * h)) & 0xFFu);          \
            bf16x8 bh[2], bl[2];                                               \
            _Pragma("unroll")                                                  \
            for (int ni = 0; ni < 2; ++ni) {                                   \
                const int off = rB[ni] * 64 + (((2 * h + kh) ^ sw7) << 3);     \
                bh[ni] = *(const bf16x8*)((cBh) + off);                        \
                bl[ni] = *(const bf16x8*)((cBl) + off);                        \
            }                                                                  \
            acc[0][0] = MFMA32(a0, bh[0], acc[0][0]);                          \
            acc[1][0] = MFMA32(a1, bh[0], acc[1][0]);                          \
            acc[0][1] = MFMA32(a0, bh[1], acc[0][1]);                          \
            acc[1][1] = MFMA32(a1, bh[1], acc[1][1]);                          \
            acc[0][0] = MFMA32(a0, bl[0], acc[0][0]);                          \
            acc[1][0] = MFMA32(a1, bl[0], acc[1][0]);                          \
            acc[0][1] = MFMA32(a0, bl[1], acc[0][1]);                          \
            acc[1][1] = MFMA32(a1, bl[1], acc[1][1]);                          \
        }                                                                      \
        WAIT_BARRIER();                                                        \
    } while (0)

#pragma unroll 1
    for (int s = 0; s < T_ / TS_; ++s) {
        {
            const char* src = (const char*)bitsIn + ((size_t)s * B_ + b) * 16384;
#pragma unroll
            for (int i = 0; i < 4; ++i)
                GL2LDS(src + (w * 4 + i) * 1024 + lane * 16,
                       bitsLds + (w * 4 + i) * 1024);
        }
        STAGEB(sBh0, sBl0, 0);
        WAIT_BARRIER();

        f32x16 acc[2][2] = {};

#pragma unroll 1
        for (int ks = 0; ks < K / 64; ks += 2) {
            STAGEB(sBh1, sBl1, (ks + 1) * 64);
            KSTEPB(ks, sBh0, sBl0);
            if (ks + 2 < K / 64)
                STAGEB(sBh0, sBl0, (ks + 2) * 64);
            KSTEPB(ks + 1, sBh1, sBl1);
        }

        u64 word0 = 0, word1 = 0;
        if (wm == 0) {
#pragma unroll
            for (int ni = 0; ni < 2; ++ni)
#pragma unroll
                for (int mi = 0; mi < 2; ++mi)
#pragma unroll
                    for (int r = 0; r < 16; ++r) {
                        const int tt = mi * 32 + (r & 3) + 8 * (r >> 2) + 4 * kh;
                        If[wn * 4096 + tt * 64 + ni * 32 + l31] = acc[mi][ni][r];
                    }
        }
        __syncthreads();
        if (tid < 128) {
            float m = cm, sp = cs;
#pragma unroll 4
            for (int tt = 0; tt < 64; ++tt) {
                m = m * 0.5f * (1.0f - sp) + Ifb[tt * 64 + scol];
                const bool fire = m > 0.3f;
                sp = fire ? 1.0f : 0.0f;
                if constexpr (WRITE_BITS) {
                    u64 bal = __ballot(fire);
                    if ((tid & 63) == tt) word0 = bal;
                }
            }
            cm = m; cs = sp;
        }
        __syncthreads();
        if (wm == 1) {
#pragma unroll
            for (int ni = 0; ni < 2; ++ni)
#pragma unroll
                for (int mi = 0; mi < 2; ++mi)
#pragma unroll
                    for (int r = 0; r < 16; ++r) {
                        const int tt = mi * 32 + (r & 3) + 8 * (r >> 2) + 4 * kh;
                        If[wn * 4096 + tt * 64 + ni * 32 + l31] = acc[mi][ni][r];
                    }
        }
        __syncthreads();
        if (tid < 128) {
            float m = cm, sp = cs;
#pragma unroll 4
            for (int tt = 0; tt < 64; ++tt) {
                m = m * 0.5f * (1.0f - sp) + Ifb[tt * 64 + scol];
                const bool fire = m > 0.3f;
                sp = fire ? 1.0f : 0.0f;
                if constexpr (WRITE_BITS) {
                    u64 bal = __ballot(fire);
                    if ((tid & 63) == tt) word1 = bal;
                }
            }
            cm = m; cs = sp;
            if constexpr (WRITE_BITS) {
                u64* dst = bitsOut + ((size_t)s * B_ + b) * 2048;
                const int j8 = (nb >> 6) + (tid >> 6);
                const int t0 = tid & 63, t1 = 64 + (tid & 63);
                dst[t0 * 16 + (j8 ^ (t0 & 15))] = word0;
                dst[t1 * 16 + (j8 ^ (t1 & 15))] = word1;
            } else {
                if (s == T_ / TS_ - 1)
                    outp[(size_t)b * N + nb + tid] = cs;
            }
        }
        __syncthreads();
    }
#undef STAGEB
#undef KSTEPB
}

extern "C" void kernel_launch(void* const* d_in, const int* in_sizes, int n_in,
                              void* d_out, int out_size, void* d_ws, size_t ws_size,
                              hipStream_t stream)
{
    const float* x  = (const float*)d_in[0];
    const float* w0 = (const float*)d_in[1];
    const float* w1 = (const float*)d_in[2];
    const float* w2 = (const float*)d_in[3];
    float* out = (float*)d_out;

    char* p = (char*)d_ws;
    bf16* w0h = (bf16*)p;  p += (size_t)N1_ * D0_ * 2;
    bf16* w0l = (bf16*)p;  p += (size_t)N1_ * D0_ * 2;
    bf16* w1h = (bf16*)p;  p += (size_t)N2_ * N1_ * 2;
    bf16* w1l = (bf16*)p;  p += (size_t)N2_ * N1_ * 2;
    bf16* w2h = (bf16*)p;  p += (size_t)N3_ * N2_ * 2;
    bf16* w2l = (bf16*)p;  p += (size_t)N3_ * N2_ * 2;
    bf16* Xh  = (bf16*)p;  p += (size_t)T_ * B_ * D0_ * 2;          // 67 MB
    bf16* Xl  = (bf16*)p;  p += (size_t)T_ * B_ * D0_ * 2;          // 67 MB
    u64* bits0 = (u64*)p;  p += (size_t)(T_/TS_) * B_ * TS_ * (N1_/8);  // 8.4 MB
    u64* bits1 = (u64*)p;  p += (size_t)(T_/TS_) * B_ * TS_ * (N2_/8);  // 8.4 MB

    split_w<<<dim3(D0_/32, N1_/32), 256, 0, stream>>>(w0, w0h, w0l, D0_, N1_);
    split_w<<<dim3(N1_/32, N2_/32), 256, 0, stream>>>(w1, w1h, w1l, N1_, N2_);
    split_w<<<dim3(N2_/32, N3_/32), 256, 0, stream>>>(w2, w2h, w2l, N2_, N3_);
    split_x<<<dim3(D0_/32, T_/32, B_), 256, 0, stream>>>(x, Xh, Xl);

    // L0: X@w0 (3-term split) + LIF -> bit train (XCD-grouped flat grid)
    snn_layer0<<<dim3(B_ * (N1_/128)), 256, 0, stream>>>(Xh, Xl, w0h, w0l, bits0);
    // L1: bits0@w1 + LIF -> bit train (nb fastest -> panel per XCD)
    snn_layer_bits<true ><<<dim3(N2_/128, B_), 256, 0, stream>>>(
        bits0, w1h, w1l, bits1, nullptr, N2_);
    // L2: bits1@w2 + LIF -> final spikes to d_out
    snn_layer_bits<false><<<dim3(N3_/128, B_), 256, 0, stream>>>(
        bits1, w2h, w2l, nullptr, out, N3_);
}